// Round 1
// baseline (566.799 us; speedup 1.0000x reference)
//
#include <hip/hip_runtime.h>

#define D 256

// ---------------- CSR build ----------------
__global__ void hist_kernel(const int* __restrict__ dst, int* __restrict__ counts, int E) {
    int i = blockIdx.x * blockDim.x + threadIdx.x;
    if (i < E) atomicAdd(&counts[dst[i]], 1);
}

__global__ void scan_kernel(const int* __restrict__ counts, int* __restrict__ offsets, int n) {
    __shared__ int tmp[1024];
    int tid = threadIdx.x;
    int carry = 0;
    for (int base = 0; base < n; base += 1024) {
        int i = base + tid;
        int v = (i < n) ? counts[i] : 0;
        tmp[tid] = v;
        __syncthreads();
#pragma unroll
        for (int off = 1; off < 1024; off <<= 1) {
            int t = (tid >= off) ? tmp[tid - off] : 0;
            __syncthreads();
            tmp[tid] += t;
            __syncthreads();
        }
        if (i < n) offsets[i + 1] = carry + tmp[tid];
        carry += tmp[1023];
        __syncthreads();
    }
    if (tid == 0) offsets[0] = 0;
}

__global__ void fill_kernel(const int* __restrict__ dst, const int* __restrict__ offsets,
                            int* __restrict__ cursor, int* __restrict__ edge_ids, int E) {
    int i = blockIdx.x * blockDim.x + threadIdx.x;
    if (i < E) {
        int d = dst[i];
        int p = offsets[d] + atomicAdd(&cursor[d], 1);
        edge_ids[p] = i;
    }
}

// ---------------- aggregation: one wave per node ----------------
__global__ void aggregate_kernel(const float* __restrict__ h, const float* __restrict__ e,
                                 const int* __restrict__ src, const int* __restrict__ offsets,
                                 const int* __restrict__ edge_ids, float* __restrict__ hn,
                                 int n_nodes) {
    int wid = blockIdx.x * (blockDim.x >> 6) + (threadIdx.x >> 6);
    int lane = threadIdx.x & 63;
    if (wid >= n_nodes) return;
    int beg = offsets[wid], end = offsets[wid + 1];
    float4 acc = make_float4(0.f, 0.f, 0.f, 0.f);
    for (int k = beg; k < end; ++k) {
        int eid = edge_ids[k];
        int s = src[eid];
        float w = e[eid];
        float4 hv = *reinterpret_cast<const float4*>(&h[(size_t)s * D + lane * 4]);
        acc.x += hv.x * w; acc.y += hv.y * w; acc.z += hv.z * w; acc.w += hv.w * w;
    }
    int deg = end - beg;
    float inv = (deg > 0) ? (1.0f / (float)deg) : 0.0f;
    acc.x *= inv; acc.y *= inv; acc.z *= inv; acc.w *= inv;
    *reinterpret_cast<float4*>(&hn[(size_t)wid * D + lane * 4]) = acc;
}

// ---------------- fp32 GEMM: C[M,256] = relu(A[M,256] @ W[256,256]^T + bias) ----------------
__global__ __launch_bounds__(256) void gemm_bias_relu(const float* __restrict__ A,
                                                      const float* __restrict__ W,
                                                      const float* __restrict__ bias,
                                                      float* __restrict__ C, int M) {
    __shared__ float As[16][64];
    __shared__ float Ws[16][64];
    const int t = threadIdx.x;
    const int row0 = blockIdx.x * 64;
    const int col0 = blockIdx.y * 64;
    const int lr = t >> 2;   // 0..63
    const int lq = t & 3;    // 0..3
    const int ti = t & 15;
    const int tj = t >> 4;
    const int arow = row0 + lr;

    float acc[4][4] = {{0.f}};
    for (int kk = 0; kk < 256; kk += 16) {
        float4 av = make_float4(0.f, 0.f, 0.f, 0.f);
        if (arow < M) av = *reinterpret_cast<const float4*>(&A[(size_t)arow * D + kk + lq * 4]);
        float4 wv = *reinterpret_cast<const float4*>(&W[(size_t)(col0 + lr) * D + kk + lq * 4]);
        __syncthreads();
        As[lq * 4 + 0][lr] = av.x; As[lq * 4 + 1][lr] = av.y;
        As[lq * 4 + 2][lr] = av.z; As[lq * 4 + 3][lr] = av.w;
        Ws[lq * 4 + 0][lr] = wv.x; Ws[lq * 4 + 1][lr] = wv.y;
        Ws[lq * 4 + 2][lr] = wv.z; Ws[lq * 4 + 3][lr] = wv.w;
        __syncthreads();
#pragma unroll
        for (int k = 0; k < 16; ++k) {
            const float4 a = *reinterpret_cast<const float4*>(&As[k][ti * 4]);
            const float4 b = *reinterpret_cast<const float4*>(&Ws[k][tj * 4]);
            acc[0][0] += a.x * b.x; acc[0][1] += a.x * b.y; acc[0][2] += a.x * b.z; acc[0][3] += a.x * b.w;
            acc[1][0] += a.y * b.x; acc[1][1] += a.y * b.y; acc[1][2] += a.y * b.z; acc[1][3] += a.y * b.w;
            acc[2][0] += a.z * b.x; acc[2][1] += a.z * b.y; acc[2][2] += a.z * b.z; acc[2][3] += a.z * b.w;
            acc[3][0] += a.w * b.x; acc[3][1] += a.w * b.y; acc[3][2] += a.w * b.z; acc[3][3] += a.w * b.w;
        }
    }
#pragma unroll
    for (int ii = 0; ii < 4; ++ii) {
        int r = row0 + ti * 4 + ii;
        if (r < M) {
            float4 o;
            o.x = fmaxf(acc[ii][0] + bias[col0 + tj * 4 + 0], 0.f);
            o.y = fmaxf(acc[ii][1] + bias[col0 + tj * 4 + 1], 0.f);
            o.z = fmaxf(acc[ii][2] + bias[col0 + tj * 4 + 2], 0.f);
            o.w = fmaxf(acc[ii][3] + bias[col0 + tj * 4 + 3], 0.f);
            *reinterpret_cast<float4*>(&C[(size_t)r * D + col0 + tj * 4]) = o;
        }
    }
}

// ---------------- BatchNorm ----------------
__global__ void bn_stats_kernel(const float* __restrict__ x, float* __restrict__ sums,
                                float* __restrict__ sumsq, int n) {
    int c = threadIdx.x;  // 256 threads, one column each
    float s = 0.f, s2 = 0.f;
    for (int r = blockIdx.x; r < n; r += gridDim.x) {
        float v = x[(size_t)r * D + c];
        s += v; s2 += v * v;
    }
    atomicAdd(&sums[c], s);
    atomicAdd(&sumsq[c], s2);
}

__global__ void bn_finalize_kernel(const float* __restrict__ sums, const float* __restrict__ sumsq,
                                   const float* __restrict__ gamma, const float* __restrict__ beta,
                                   float* __restrict__ scaleshift, int n) {
    int c = threadIdx.x;
    float mu = sums[c] / (float)n;
    float var = sumsq[c] / (float)n - mu * mu;
    float rs = rsqrtf(var + 1e-5f);
    float sc = gamma[c] * rs;
    scaleshift[c] = sc;
    scaleshift[D + c] = beta[c] - mu * sc;
}

__global__ void bn_apply_kernel(float* __restrict__ x, const float* __restrict__ hn,
                                const float* __restrict__ scaleshift, long total4) {
    long i = (long)blockIdx.x * blockDim.x + threadIdx.x;
    if (i >= total4) return;
    int c4 = (int)(i & 63);
    float4 v = reinterpret_cast<float4*>(x)[i];
    float4 hv = reinterpret_cast<const float4*>(hn)[i];
    float4 sc = reinterpret_cast<const float4*>(scaleshift)[c4];
    float4 sh = reinterpret_cast<const float4*>(scaleshift)[64 + c4];
    v.x = v.x * sc.x + sh.x + hv.x;
    v.y = v.y * sc.y + sh.y + hv.y;
    v.z = v.z * sc.z + sh.z + hv.z;
    v.w = v.w * sc.w + sh.w + hv.w;
    reinterpret_cast<float4*>(x)[i] = v;
}

extern "C" void kernel_launch(void* const* d_in, const int* in_sizes, int n_in,
                              void* d_out, int out_size, void* d_ws, size_t ws_size,
                              hipStream_t stream) {
    const float* h     = (const float*)d_in[0];
    const float* e     = (const float*)d_in[1];
    const int*   src   = (const int*)d_in[2];
    const int*   dst   = (const int*)d_in[3];
    const float* W1    = (const float*)d_in[4];
    const float* b1    = (const float*)d_in[5];
    const float* W2    = (const float*)d_in[6];
    const float* b2    = (const float*)d_in[7];
    const float* gamma = (const float*)d_in[8];
    const float* beta  = (const float*)d_in[9];
    float* out = (float*)d_out;

    const int N = in_sizes[0] / D;
    const int E = in_sizes[2];

    char* ws = (char*)d_ws;
    float* hn = (float*)ws;          ws += (size_t)N * D * sizeof(float);
    float* x1 = (float*)ws;          ws += (size_t)N * D * sizeof(float);
    float* sums = (float*)ws;        ws += D * sizeof(float);
    float* sumsq = (float*)ws;       ws += D * sizeof(float);
    float* scaleshift = (float*)ws;  ws += 2 * D * sizeof(float);
    int* offsets = (int*)ws;         ws += (size_t)(N + 1) * sizeof(int);
    int* counts = (int*)ws;          ws += (size_t)N * sizeof(int);
    int* cursor = (int*)ws;          ws += (size_t)N * sizeof(int);
    int* edge_ids = (int*)ws;        ws += (size_t)E * sizeof(int);

    // zero: counts+cursor (adjacent), sums+sumsq+scaleshift region
    hipMemsetAsync(counts, 0, (size_t)2 * N * sizeof(int), stream);
    hipMemsetAsync(sums, 0, (size_t)2 * D * sizeof(float), stream);

    int eb = (E + 255) / 256;
    hist_kernel<<<eb, 256, 0, stream>>>(dst, counts, E);
    scan_kernel<<<1, 1024, 0, stream>>>(counts, offsets, N);
    fill_kernel<<<eb, 256, 0, stream>>>(dst, offsets, cursor, edge_ids, E);

    int ab = (N + 3) / 4;  // 4 waves per block
    aggregate_kernel<<<ab, 256, 0, stream>>>(h, e, src, offsets, edge_ids, hn, N);

    dim3 ggrid((N + 63) / 64, 4);
    gemm_bias_relu<<<ggrid, 256, 0, stream>>>(hn, W1, b1, x1, N);
    gemm_bias_relu<<<ggrid, 256, 0, stream>>>(x1, W2, b2, out, N);

    bn_stats_kernel<<<512, 256, 0, stream>>>(out, sums, sumsq, N);
    bn_finalize_kernel<<<1, 256, 0, stream>>>(sums, sumsq, gamma, beta, scaleshift, N);
    long total4 = (long)N * (D / 4);
    bn_apply_kernel<<<(int)((total4 + 255) / 256), 256, 0, stream>>>(out, hn, scaleshift, total4);
}

// Round 2
// 383.820 us; speedup vs baseline: 1.4767x; 1.4767x over previous
//
#include <hip/hip_runtime.h>

#define D 256

typedef __attribute__((ext_vector_type(8))) short bf16x8;
typedef __attribute__((ext_vector_type(4))) float f32x4;

__device__ __forceinline__ unsigned short bfr(float x) {
    unsigned u = __float_as_uint(x);
    unsigned r = (u + 0x7fffu + ((u >> 16) & 1u)) >> 16;
    return (unsigned short)r;
}
__device__ __forceinline__ float bf2f(unsigned short u) {
    return __uint_as_float(((unsigned)u) << 16);
}

// ---------------- fp32 -> bf16 convert ----------------
__global__ void cvt_kernel(const float* __restrict__ in, unsigned short* __restrict__ out, long n4) {
    long stride = (long)gridDim.x * blockDim.x;
    for (long i = (long)blockIdx.x * blockDim.x + threadIdx.x; i < n4; i += stride) {
        float4 v = reinterpret_cast<const float4*>(in)[i];
        ushort4 o;
        o.x = bfr(v.x); o.y = bfr(v.y); o.z = bfr(v.z); o.w = bfr(v.w);
        reinterpret_cast<ushort4*>(out)[i] = o;
    }
}

// ---------------- CSR build ----------------
__global__ void hist_kernel(const int* __restrict__ dst, int* __restrict__ counts, int E) {
    int i = blockIdx.x * blockDim.x + threadIdx.x;
    if (i < E) atomicAdd(&counts[dst[i]], 1);
}

__global__ void scan_kernel(const int* __restrict__ counts, int* __restrict__ offsets, int n) {
    __shared__ int tot[1024];
    int tid = threadIdx.x;
    int per = (n + 1023) >> 10;
    int beg = tid * per;
    int end = min(beg + per, n);
    int s = 0;
    for (int i = beg; i < end; ++i) s += counts[i];
    tot[tid] = s;
    __syncthreads();
    for (int off = 1; off < 1024; off <<= 1) {
        int t = (tid >= off) ? tot[tid - off] : 0;
        __syncthreads();
        tot[tid] += t;
        __syncthreads();
    }
    int run = tid ? tot[tid - 1] : 0;
    for (int i = beg; i < end; ++i) {
        run += counts[i];
        offsets[i + 1] = run;
    }
    if (tid == 0) offsets[0] = 0;
}

__global__ void fill_kernel(const int* __restrict__ src, const float* __restrict__ e,
                            const int* __restrict__ dst, const int* __restrict__ offsets,
                            int* __restrict__ cursor, int2* __restrict__ ev, int E) {
    int i = blockIdx.x * blockDim.x + threadIdx.x;
    if (i < E) {
        int d = dst[i];
        int p = offsets[d] + atomicAdd(&cursor[d], 1);
        ev[p] = make_int2(src[i], __float_as_int(e[i]));
    }
}

// ---------------- aggregation: one wave per node, bf16 gather ----------------
__global__ void aggregate_kernel(const unsigned short* __restrict__ hb, const int2* __restrict__ ev,
                                 const int* __restrict__ offsets, unsigned short* __restrict__ hnb,
                                 int n_nodes) {
    int wid = blockIdx.x * 4 + (threadIdx.x >> 6);
    if (wid >= n_nodes) return;
    int lane = threadIdx.x & 63;
    int beg = offsets[wid], end = offsets[wid + 1];
    float ax = 0.f, ay = 0.f, az = 0.f, aw = 0.f;
    int k = beg;
    for (; k + 4 <= end; k += 4) {
        int2 e0 = ev[k], e1 = ev[k + 1], e2 = ev[k + 2], e3 = ev[k + 3];
        ushort4 h0 = *reinterpret_cast<const ushort4*>(&hb[(size_t)e0.x * D + lane * 4]);
        ushort4 h1 = *reinterpret_cast<const ushort4*>(&hb[(size_t)e1.x * D + lane * 4]);
        ushort4 h2 = *reinterpret_cast<const ushort4*>(&hb[(size_t)e2.x * D + lane * 4]);
        ushort4 h3 = *reinterpret_cast<const ushort4*>(&hb[(size_t)e3.x * D + lane * 4]);
        float w0 = __int_as_float(e0.y), w1 = __int_as_float(e1.y);
        float w2 = __int_as_float(e2.y), w3 = __int_as_float(e3.y);
        ax += bf2f(h0.x) * w0 + bf2f(h1.x) * w1 + bf2f(h2.x) * w2 + bf2f(h3.x) * w3;
        ay += bf2f(h0.y) * w0 + bf2f(h1.y) * w1 + bf2f(h2.y) * w2 + bf2f(h3.y) * w3;
        az += bf2f(h0.z) * w0 + bf2f(h1.z) * w1 + bf2f(h2.z) * w2 + bf2f(h3.z) * w3;
        aw += bf2f(h0.w) * w0 + bf2f(h1.w) * w1 + bf2f(h2.w) * w2 + bf2f(h3.w) * w3;
    }
    for (; k < end; ++k) {
        int2 e0 = ev[k];
        ushort4 h0 = *reinterpret_cast<const ushort4*>(&hb[(size_t)e0.x * D + lane * 4]);
        float w0 = __int_as_float(e0.y);
        ax += bf2f(h0.x) * w0; ay += bf2f(h0.y) * w0;
        az += bf2f(h0.z) * w0; aw += bf2f(h0.w) * w0;
    }
    int deg = end - beg;
    float inv = (deg > 0) ? (1.0f / (float)deg) : 0.0f;
    ushort4 o;
    o.x = bfr(ax * inv); o.y = bfr(ay * inv); o.z = bfr(az * inv); o.w = bfr(aw * inv);
    *reinterpret_cast<ushort4*>(&hnb[(size_t)wid * D + lane * 4]) = o;
}

// ---------------- bf16 MFMA GEMM: C[M,256] = relu(A[M,256] @ W[256,256]^T + bias) ----------------
// A bf16, W fp32 (converted in staging), out bf16 (OUT_BF16=1) or fp32 (=0).
template <int OUT_BF16>
__global__ __launch_bounds__(256) void gemm_kernel(const unsigned short* __restrict__ A,
                                                   const float* __restrict__ W,
                                                   const float* __restrict__ bias,
                                                   void* __restrict__ Cout, int M) {
    __shared__ short As[64 * 256];
    __shared__ short Ws[64 * 256];
    const int t = threadIdx.x;
    const int row0 = blockIdx.x * 64;
    const int col0 = blockIdx.y * 64;

    // stage A tile (bf16, 32KB), XOR-swizzled rows
#pragma unroll
    for (int it = 0; it < 8; ++it) {
        int p = it * 4096 + t * 16;   // dest byte in tile
        int r = p >> 9;               // tile row (512B per row)
        int grow = row0 + r;
        float4 v = make_float4(0.f, 0.f, 0.f, 0.f);
        if (grow < M)
            v = *reinterpret_cast<const float4*>(reinterpret_cast<const char*>(A) +
                                                 (size_t)grow * 512 + (p & 511));
        *reinterpret_cast<float4*>(reinterpret_cast<char*>(As) + (p ^ ((r & 7) << 4))) = v;
    }
    // stage W tile (fp32 -> bf16, rows col0..col0+63)
#pragma unroll
    for (int it = 0; it < 8; ++it) {
        int p = it * 4096 + t * 16;
        int r = p >> 9;
        const float* wsrc = W + (size_t)(col0 + r) * D + ((p & 511) >> 1);
        float4 w0 = *reinterpret_cast<const float4*>(wsrc);
        float4 w1 = *reinterpret_cast<const float4*>(wsrc + 4);
        bf16x8 pk;
        pk[0] = (short)bfr(w0.x); pk[1] = (short)bfr(w0.y);
        pk[2] = (short)bfr(w0.z); pk[3] = (short)bfr(w0.w);
        pk[4] = (short)bfr(w1.x); pk[5] = (short)bfr(w1.y);
        pk[6] = (short)bfr(w1.z); pk[7] = (short)bfr(w1.w);
        *reinterpret_cast<bf16x8*>(reinterpret_cast<char*>(Ws) + (p ^ ((r & 7) << 4))) = pk;
    }
    __syncthreads();

    const int lane = t & 63;
    const int w = t >> 6;
    const int wr = (w >> 1) * 32;   // wave row base in tile
    const int wc = (w & 1) * 32;    // wave col base in tile
    const int lr = lane & 15;
    const int q = lane >> 4;
    const int swz = (lane & 7) << 4;

    f32x4 zero = {0.f, 0.f, 0.f, 0.f};
    f32x4 acc[2][2] = {{zero, zero}, {zero, zero}};

#pragma unroll
    for (int k0 = 0; k0 < 256; k0 += 32) {
        int kb = k0 * 2 + q * 16;
        bf16x8 a0 = *reinterpret_cast<const bf16x8*>(reinterpret_cast<const char*>(As) +
                                                     (((wr + lr) * 512 + kb) ^ swz));
        bf16x8 a1 = *reinterpret_cast<const bf16x8*>(reinterpret_cast<const char*>(As) +
                                                     (((wr + 16 + lr) * 512 + kb) ^ swz));
        bf16x8 b0 = *reinterpret_cast<const bf16x8*>(reinterpret_cast<const char*>(Ws) +
                                                     (((wc + lr) * 512 + kb) ^ swz));
        bf16x8 b1 = *reinterpret_cast<const bf16x8*>(reinterpret_cast<const char*>(Ws) +
                                                     (((wc + 16 + lr) * 512 + kb) ^ swz));
        acc[0][0] = __builtin_amdgcn_mfma_f32_16x16x32_bf16(a0, b0, acc[0][0], 0, 0, 0);
        acc[0][1] = __builtin_amdgcn_mfma_f32_16x16x32_bf16(a0, b1, acc[0][1], 0, 0, 0);
        acc[1][0] = __builtin_amdgcn_mfma_f32_16x16x32_bf16(a1, b0, acc[1][0], 0, 0, 0);
        acc[1][1] = __builtin_amdgcn_mfma_f32_16x16x32_bf16(a1, b1, acc[1][1], 0, 0, 0);
    }

#pragma unroll
    for (int i = 0; i < 2; ++i) {
#pragma unroll
        for (int j = 0; j < 2; ++j) {
            int col = col0 + wc + j * 16 + lr;
            float bv = bias[col];
#pragma unroll
            for (int r = 0; r < 4; ++r) {
                int row = row0 + wr + i * 16 + q * 4 + r;
                if (row < M) {
                    float v = fmaxf(acc[i][j][r] + bv, 0.f);
                    if (OUT_BF16)
                        ((unsigned short*)Cout)[(size_t)row * D + col] = bfr(v);
                    else
                        ((float*)Cout)[(size_t)row * D + col] = v;
                }
            }
        }
    }
}

// ---------------- BatchNorm: partial stats, finalize, apply ----------------
__global__ void bn_stats1_kernel(const float* __restrict__ x, float* __restrict__ partial, int n) {
    __shared__ float4 rs[4][64];
    __shared__ float4 rq[4][64];
    int t = threadIdx.x;
    int lane = t & 63, w = t >> 6;
    int gw = blockIdx.x * 4 + w;
    float4 s = make_float4(0.f, 0.f, 0.f, 0.f);
    float4 q = make_float4(0.f, 0.f, 0.f, 0.f);
    for (int r = gw; r < n; r += 2048) {
        float4 v = *reinterpret_cast<const float4*>(&x[(size_t)r * D + lane * 4]);
        s.x += v.x; s.y += v.y; s.z += v.z; s.w += v.w;
        q.x += v.x * v.x; q.y += v.y * v.y; q.z += v.z * v.z; q.w += v.w * v.w;
    }
    rs[w][lane] = s; rq[w][lane] = q;
    __syncthreads();
    if (t < 64) {
        float4 S = rs[0][t], Q = rq[0][t];
        for (int i = 1; i < 4; ++i) {
            float4 a = rs[i][t], b = rq[i][t];
            S.x += a.x; S.y += a.y; S.z += a.z; S.w += a.w;
            Q.x += b.x; Q.y += b.y; Q.z += b.z; Q.w += b.w;
        }
        *reinterpret_cast<float4*>(&partial[(size_t)blockIdx.x * 512 + t * 4]) = S;
        *reinterpret_cast<float4*>(&partial[(size_t)blockIdx.x * 512 + 256 + t * 4]) = Q;
    }
}

__global__ void bn_finalize_kernel(const float* __restrict__ partial, const float* __restrict__ gamma,
                                   const float* __restrict__ beta, float* __restrict__ scaleshift,
                                   int n) {
    int c = threadIdx.x;
    float s = 0.f, q = 0.f;
    for (int b = 0; b < 512; ++b) {
        s += partial[(size_t)b * 512 + c];
        q += partial[(size_t)b * 512 + 256 + c];
    }
    float mu = s / (float)n;
    float var = q / (float)n - mu * mu;
    float rs = rsqrtf(var + 1e-5f);
    float sc = gamma[c] * rs;
    scaleshift[c] = sc;
    scaleshift[D + c] = beta[c] - mu * sc;
}

__global__ void bn_apply_kernel(float* __restrict__ x, const unsigned short* __restrict__ hnb,
                                const float* __restrict__ scaleshift, long total4) {
    long stride = (long)gridDim.x * blockDim.x;
    for (long i = (long)blockIdx.x * blockDim.x + threadIdx.x; i < total4; i += stride) {
        int c4 = (int)(i & 63);
        float4 v = reinterpret_cast<float4*>(x)[i];
        ushort4 hu = reinterpret_cast<const ushort4*>(hnb)[i];
        float4 sc = reinterpret_cast<const float4*>(scaleshift)[c4];
        float4 sh = reinterpret_cast<const float4*>(scaleshift)[64 + c4];
        v.x = v.x * sc.x + sh.x + bf2f(hu.x);
        v.y = v.y * sc.y + sh.y + bf2f(hu.y);
        v.z = v.z * sc.z + sh.z + bf2f(hu.z);
        v.w = v.w * sc.w + sh.w + bf2f(hu.w);
        reinterpret_cast<float4*>(x)[i] = v;
    }
}

extern "C" void kernel_launch(void* const* d_in, const int* in_sizes, int n_in,
                              void* d_out, int out_size, void* d_ws, size_t ws_size,
                              hipStream_t stream) {
    const float* h     = (const float*)d_in[0];
    const float* e     = (const float*)d_in[1];
    const int*   src   = (const int*)d_in[2];
    const int*   dst   = (const int*)d_in[3];
    const float* W1    = (const float*)d_in[4];
    const float* b1    = (const float*)d_in[5];
    const float* W2    = (const float*)d_in[6];
    const float* b2    = (const float*)d_in[7];
    const float* gamma = (const float*)d_in[8];
    const float* beta  = (const float*)d_in[9];
    float* out = (float*)d_out;

    const int N = in_sizes[0] / D;
    const int E = in_sizes[2];
    const size_t NB = (size_t)N * D;

    char* ws = (char*)d_ws;
    unsigned short* h_bf = (unsigned short*)ws; ws += NB * 2;      // 25.6 MB
    unsigned short* hnb  = (unsigned short*)ws; ws += NB * 2;      // 25.6 MB
    unsigned short* x1b  = (unsigned short*)ws; ws += NB * 2;      // 25.6 MB
    int2* ev             = (int2*)ws;           ws += (size_t)E * 8;
    float* partial       = (float*)ws;          ws += (size_t)512 * 512 * 4;
    float* scaleshift    = (float*)ws;          ws += 2 * D * sizeof(float);
    int* offsets         = (int*)ws;            ws += (size_t)(N + 1) * 4;
    int* counts          = (int*)ws;            ws += (size_t)N * 4;
    int* cursor          = (int*)ws;            ws += (size_t)N * 4;

    hipMemsetAsync(counts, 0, (size_t)2 * N * 4, stream);

    cvt_kernel<<<2048, 256, 0, stream>>>(h, h_bf, (long)(NB / 4));

    int eb = (E + 255) / 256;
    hist_kernel<<<eb, 256, 0, stream>>>(dst, counts, E);
    scan_kernel<<<1, 1024, 0, stream>>>(counts, offsets, N);
    fill_kernel<<<eb, 256, 0, stream>>>(src, e, dst, offsets, cursor, ev, E);

    aggregate_kernel<<<(N + 3) / 4, 256, 0, stream>>>(h_bf, ev, offsets, hnb, N);

    dim3 ggrid((N + 63) / 64, 4);
    gemm_kernel<1><<<ggrid, 256, 0, stream>>>(hnb, W1, b1, x1b, N);
    gemm_kernel<0><<<ggrid, 256, 0, stream>>>(x1b, W2, b2, out, N);

    bn_stats1_kernel<<<512, 256, 0, stream>>>(out, partial, N);
    bn_finalize_kernel<<<1, 256, 0, stream>>>(partial, gamma, beta, scaleshift, N);
    bn_apply_kernel<<<2048, 256, 0, stream>>>(out, hnb, scaleshift, (long)(NB / 4));
}